// Round 1
// baseline (620.990 us; speedup 1.0000x reference)
//
#include <hip/hip_runtime.h>
#include <stdint.h>

#define ROWS 150528              // 1024 * 147
#define QSCALE 0.17677669529663687f

typedef __attribute__((ext_vector_type(8))) __bf16 bf16x8;
typedef __attribute__((ext_vector_type(4))) __bf16 bf16x4;
typedef __attribute__((ext_vector_type(4))) float f32x4;
typedef __attribute__((ext_vector_type(4))) float f4;

static __device__ __forceinline__ f32x4 mfma_bf16(bf16x8 a, bf16x8 b, f32x4 c) {
  return __builtin_amdgcn_mfma_f32_16x16x32_bf16(a, b, c, 0, 0, 0);
}

// ---- convert f32 -> bf16 (n4 float4 groups) ----
__global__ void cvt_bf16(const float* __restrict__ src, __bf16* __restrict__ dst, int n4) {
  int i = blockIdx.x * 256 + threadIdx.x;
  if (i >= n4) return;
  f4 v = ((const f4*)src)[i];
  bf16x4 b;
  b[0] = (__bf16)v[0]; b[1] = (__bf16)v[1]; b[2] = (__bf16)v[2]; b[3] = (__bf16)v[3];
  ((bf16x4*)dst)[i] = b;
}

// ---- GEMM: out[M x 192] = X[M x 192] @ W^T + bias, optional scale ----
// W pre-converted to bf16 row-major (out_feat, in_feat): B[k][n] = W[n][k] contiguous in k.
template<bool IN_F32, bool OUT_F32>
__global__ __launch_bounds__(512)
void gemm192(const void* __restrict__ Xv, const __bf16* __restrict__ Wb,
             const float* __restrict__ bias, void* Ov, float scale)
{
  __shared__ __align__(16) __bf16 Xs[128 * 200];   // pad 192->200: 2-way banks (free)
  const int tid = threadIdx.x;
  const int row0 = blockIdx.x * 128;

  if (IN_F32) {
    const f4* X4 = (const f4*)Xv;
    #pragma unroll
    for (int p = 0; p < 12; ++p) {
      int i = tid + p * 512;               // 128*48 float4
      int r = i / 48, c4 = i % 48;
      f4 v = X4[(size_t)row0 * 48 + i];
      bf16x4 bb;
      bb[0] = (__bf16)v[0]; bb[1] = (__bf16)v[1]; bb[2] = (__bf16)v[2]; bb[3] = (__bf16)v[3];
      *(bf16x4*)&Xs[r * 200 + c4 * 4] = bb;
    }
  } else {
    const bf16x8* X8 = (const bf16x8*)Xv;
    #pragma unroll
    for (int p = 0; p < 6; ++p) {
      int i = tid + p * 512;               // 128*24 bf16x8
      int r = i / 24, c8 = i % 24;
      *(bf16x8*)&Xs[r * 200 + c8 * 8] = X8[(size_t)row0 * 24 + i];
    }
  }
  __syncthreads();

  const int wv = tid >> 6, lane = tid & 63;
  const int lr = lane & 15, lg = lane >> 4;

  const __bf16* xrow = &Xs[(wv * 16 + lr) * 200];
  bf16x8 a[6];
  #pragma unroll
  for (int kk = 0; kk < 6; ++kk) a[kk] = *(const bf16x8*)&xrow[kk * 32 + lg * 8];

  #pragma unroll
  for (int nt = 0; nt < 12; ++nt) {
    f32x4 acc = {0.f, 0.f, 0.f, 0.f};
    const __bf16* wrow = &Wb[(nt * 16 + lr) * 192 + lg * 8];
    #pragma unroll
    for (int kk = 0; kk < 6; ++kk) {
      bf16x8 b = *(const bf16x8*)&wrow[kk * 32];
      acc = mfma_bf16(a[kk], b, acc);
    }
    const int col = nt * 16 + lr;
    const float bv = bias[col];
    const int grow = row0 + wv * 16 + lg * 4;
    if (OUT_F32) {
      float* O = (float*)Ov;
      #pragma unroll
      for (int j = 0; j < 4; ++j)
        O[(size_t)(grow + j) * 192 + col] = (acc[j] + bv) * scale;
    } else {
      __bf16* O = (__bf16*)Ov;
      #pragma unroll
      for (int j = 0; j < 4; ++j)
        O[(size_t)(grow + j) * 192 + col] = (__bf16)((acc[j] + bv) * scale);
    }
  }
}

// ---- attention: one block per (b, h); Nq=Nkv=147, hd=32 ----
__global__ __launch_bounds__(256)
void attn147(const __bf16* Q, const __bf16* __restrict__ K,
             const __bf16* __restrict__ V, __bf16* O,
             const float* __restrict__ maskp, const float* __restrict__ btab)
{
  __shared__ float bm[49 * 49];                       // combined mask + rel-pos bias
  __shared__ __align__(16) __bf16 Vt[32 * 168];       // V^T: [d][key], pad 168
  __shared__ __align__(16) __bf16 Pl[4][16 * 168];    // per-wave P tile [qrow][key]

  const int b = blockIdx.x, h = blockIdx.y;
  const int win = b & 63;
  const int tid = threadIdx.x;
  const size_t bOff = (size_t)b * 147;

  // stage combined (mask + bias) 49x49 tile
  for (int i = tid; i < 2401; i += 256) {
    int q49 = i / 49, k49 = i % 49;
    int qi = q49 / 7, qj = q49 % 7, ki = k49 / 7, kj = k49 % 7;
    int rel = (qi - ki + 6) * 13 + (qj - kj + 6);
    bm[i] = maskp[win * 2401 + i] + btab[rel * 6 + h];
  }
  // stage V transposed (d-major) ; zero the key-tail [147,168)
  for (int i = tid; i < 147 * 32; i += 256) {
    int key = i >> 5, d = i & 31;
    Vt[d * 168 + key] = V[(bOff + key) * 192 + h * 32 + d];
  }
  for (int i = tid; i < 32 * 21; i += 256) {
    int d = i / 21, key = 147 + i % 21;
    Vt[d * 168 + key] = (__bf16)0.f;
  }
  __syncthreads();

  const int wv = tid >> 6, lane = tid & 63;
  const int lr = lane & 15, lg = lane >> 4;

  for (int mt = wv; mt < 10; mt += 4) {
    int qr = mt * 16 + lr; if (qr > 146) qr = 146;   // clamp tail (rows discarded)
    bf16x8 aq = *(const bf16x8*)&Q[(bOff + qr) * 192 + h * 32 + lg * 8];

    // S = (q*scale) . k^T : A=Q[q][kdim], B=K^T[kdim][key]=K[key][kdim] (contig)
    f32x4 s[10];
    #pragma unroll
    for (int kt = 0; kt < 10; ++kt) {
      int kr = kt * 16 + lr; if (kr > 146) kr = 146;
      bf16x8 bk = *(const bf16x8*)&K[(bOff + kr) * 192 + h * 32 + lg * 8];
      f32x4 z = {0.f, 0.f, 0.f, 0.f};
      s[kt] = mfma_bf16(aq, bk, z);
    }

    int q49v[4];
    #pragma unroll
    for (int j = 0; j < 4; ++j) q49v[j] = (mt * 16 + lg * 4 + j) % 49;

    #pragma unroll
    for (int kt = 0; kt < 10; ++kt) {
      int ka = kt * 16 + lr;
      bool kval = ka < 147;
      int k49 = ka % 49;
      #pragma unroll
      for (int j = 0; j < 4; ++j) {
        float v = s[kt][j] + bm[q49v[j] * 49 + k49];
        s[kt][j] = kval ? v : -1e30f;
      }
    }

    // softmax per q-row: rows live in one 16-lane group; cols = 10 kt x 16 lanes
    float r4[4];
    #pragma unroll
    for (int j = 0; j < 4; ++j) {
      float m = s[0][j];
      #pragma unroll
      for (int kt = 1; kt < 10; ++kt) m = fmaxf(m, s[kt][j]);
      m = fmaxf(m, __shfl_xor(m, 1));
      m = fmaxf(m, __shfl_xor(m, 2));
      m = fmaxf(m, __shfl_xor(m, 4));
      m = fmaxf(m, __shfl_xor(m, 8));
      float sum = 0.f;
      #pragma unroll
      for (int kt = 0; kt < 10; ++kt) {
        float e = exp2f((s[kt][j] - m) * 1.44269504088896f);
        s[kt][j] = e;
        sum += e;
      }
      sum += __shfl_xor(sum, 1);
      sum += __shfl_xor(sum, 2);
      sum += __shfl_xor(sum, 4);
      sum += __shfl_xor(sum, 8);
      r4[j] = 1.f / sum;     // applied to O rows (same lane mapping), P left unnormalized
    }

    // P -> LDS (transpose for PV A-operand)
    #pragma unroll
    for (int kt = 0; kt < 10; ++kt) {
      #pragma unroll
      for (int j = 0; j < 4; ++j)
        Pl[wv][(lg * 4 + j) * 168 + kt * 16 + lr] = (__bf16)s[kt][j];
    }

    // O = P @ V : A=P[q][key] from Pl, B=V[key][d] from Vt (d-major -> contig in key)
    f32x4 o0 = {0,0,0,0}, o1 = {0,0,0,0};
    #pragma unroll
    for (int ks = 0; ks < 5; ++ks) {
      bf16x8 ap = *(const bf16x8*)&Pl[wv][lr * 168 + ks * 32 + lg * 8];
      bf16x8 b0 = *(const bf16x8*)&Vt[lr * 168 + ks * 32 + lg * 8];
      bf16x8 b1 = *(const bf16x8*)&Vt[(16 + lr) * 168 + ks * 32 + lg * 8];
      o0 = mfma_bf16(ap, b0, o0);
      o1 = mfma_bf16(ap, b1, o1);
    }
    #pragma unroll
    for (int j = 0; j < 4; ++j) {
      int qa = mt * 16 + lg * 4 + j;
      if (qa < 147) {
        size_t base = (bOff + qa) * 192 + h * 32;
        O[base + lr]      = (__bf16)(o0[j] * r4[j]);
        O[base + 16 + lr] = (__bf16)(o1[j] * r4[j]);
      }
    }
  }
}

extern "C" void kernel_launch(void* const* d_in, const int* in_sizes, int n_in,
                              void* d_out, int out_size, void* d_ws, size_t ws_size,
                              hipStream_t stream) {
  (void)in_sizes; (void)n_in; (void)out_size;
  const float* x_q  = (const float*)d_in[0];
  const float* x_k  = (const float*)d_in[1];
  const float* x_v  = (const float*)d_in[2];
  const float* maskp= (const float*)d_in[3];
  const float* q_w  = (const float*)d_in[4];
  const float* q_b  = (const float*)d_in[5];
  const float* k_w  = (const float*)d_in[6];
  const float* k_b  = (const float*)d_in[7];
  const float* v_w  = (const float*)d_in[8];
  const float* v_b  = (const float*)d_in[9];
  const float* p_w  = (const float*)d_in[10];
  const float* p_b  = (const float*)d_in[11];
  const float* btab = (const float*)d_in[12];

  char* ws = (char*)d_ws;
  const size_t wsz = 36864 * sizeof(__bf16);     // one 192x192 bf16 weight
  __bf16* wq = (__bf16*)ws;
  __bf16* wk = (__bf16*)(ws + wsz);
  __bf16* wv = (__bf16*)(ws + 2 * wsz);
  __bf16* wp = (__bf16*)(ws + 3 * wsz);
  char* bufs = ws + 4 * wsz;                     // 294912 bytes in
  const size_t sz = (size_t)ROWS * 192 * sizeof(__bf16);   // 57.8 MB
  __bf16* qb = (__bf16*)bufs;
  __bf16* kb = (__bf16*)(bufs + sz);
  __bf16* vb = (__bf16*)(bufs + 2 * sz);
  // o buffer: separate region if workspace allows, else alias q (safe: per-(b,h)
  // region is read fully before being written by the same wave, disjoint across waves)
  __bf16* ob = (ws_size >= 4 * wsz + 4 * sz) ? (__bf16*)(bufs + 3 * sz) : qb;

  cvt_bf16<<<36, 256, 0, stream>>>(q_w, wq, 9216);
  cvt_bf16<<<36, 256, 0, stream>>>(k_w, wk, 9216);
  cvt_bf16<<<36, 256, 0, stream>>>(v_w, wv, 9216);
  cvt_bf16<<<36, 256, 0, stream>>>(p_w, wp, 9216);

  gemm192<true, false><<<ROWS / 128, 512, 0, stream>>>(x_q, wq, q_b, qb, QSCALE);
  gemm192<true, false><<<ROWS / 128, 512, 0, stream>>>(x_k, wk, k_b, kb, 1.f);
  gemm192<true, false><<<ROWS / 128, 512, 0, stream>>>(x_v, wv, v_b, vb, 1.f);

  attn147<<<dim3(1024, 6), 256, 0, stream>>>(qb, kb, vb, ob, maskp, btab);

  gemm192<false, true><<<ROWS / 128, 512, 0, stream>>>(ob, wp, p_b, d_out, 1.f);
}

// Round 2
// 436.283 us; speedup vs baseline: 1.4234x; 1.4234x over previous
//
#include <hip/hip_runtime.h>
#include <stdint.h>

#define ROWS 150528              // 1024 * 147
#define QSCALE 0.17677669529663687f

typedef __attribute__((ext_vector_type(8))) __bf16 bf16x8;
typedef __attribute__((ext_vector_type(4))) __bf16 bf16x4;
typedef __attribute__((ext_vector_type(4))) float f32x4;
typedef __attribute__((ext_vector_type(4))) float f4;

static __device__ __forceinline__ f32x4 mfma_bf16(bf16x8 a, bf16x8 b, f32x4 c) {
  return __builtin_amdgcn_mfma_f32_16x16x32_bf16(a, b, c, 0, 0, 0);
}

static __device__ __forceinline__ uint32_t pack_bf16(float a, float b) {
  uint16_t ux = __builtin_bit_cast(uint16_t, (__bf16)a);
  uint16_t uy = __builtin_bit_cast(uint16_t, (__bf16)b);
  return (uint32_t)ux | ((uint32_t)uy << 16);
}

// ---- convert 4 f32 weights -> bf16 in one launch: grid (36, 4) ----
__global__ void cvt4(const float* s0, const float* s1, const float* s2, const float* s3,
                     __bf16* d0, __bf16* d1, __bf16* d2, __bf16* d3) {
  const int y = blockIdx.y;
  const float* s = y == 0 ? s0 : y == 1 ? s1 : y == 2 ? s2 : s3;
  __bf16* d = y == 0 ? d0 : y == 1 ? d1 : y == 2 ? d2 : d3;
  int i = blockIdx.x * 256 + threadIdx.x;        // 9216 float4 groups
  f4 v = ((const f4*)s)[i];
  bf16x4 b;
  b[0] = (__bf16)v[0]; b[1] = (__bf16)v[1]; b[2] = (__bf16)v[2]; b[3] = (__bf16)v[3];
  ((bf16x4*)d)[i] = b;
}

// ---- GEMM v2: out[M x 192] = X[M x 192] @ W^T * scale-ish + bias ----
// 256 thr / 4 waves; wave owns n-tiles {w, w+4, w+8}; W-frags register-resident.
template<bool IN_F32, bool OUT_F32>
__global__ __launch_bounds__(256, 3)
void gemmv2(const void* __restrict__ Xv, const __bf16* __restrict__ Wb,
            const float* __restrict__ bias, void* __restrict__ Ov, float scale)
{
  __shared__ __align__(16) __bf16 Xs[64 * 200];   // pad 192->200
  const int tid = threadIdx.x;
  const int wv = tid >> 6, lane = tid & 63, lr = lane & 15, lg = lane >> 4;
  const size_t row0 = (size_t)blockIdx.x * 64;

  // W fragments: loop-invariant, 18 x b128 from L2-hot 72KB weight
  bf16x8 wf[3][6];
  float bcol[3];
  #pragma unroll
  for (int t = 0; t < 3; ++t) {
    const int nt = wv + 4 * t;
    const __bf16* wr = &Wb[(nt * 16 + lr) * 192 + lg * 8];
    #pragma unroll
    for (int kk = 0; kk < 6; ++kk) wf[t][kk] = *(const bf16x8*)&wr[kk * 32];
    bcol[t] = bias[nt * 16 + lr] * scale;
  }

  if (IN_F32) {
    const f4* X4 = (const f4*)Xv + row0 * 48;
    #pragma unroll
    for (int p = 0; p < 12; ++p) {
      int i = tid + p * 256;                     // 64*48 float4
      int r = i / 48, c = i % 48;
      f4 v = X4[i];
      bf16x4 bb;
      bb[0] = (__bf16)v[0]; bb[1] = (__bf16)v[1]; bb[2] = (__bf16)v[2]; bb[3] = (__bf16)v[3];
      *(bf16x4*)&Xs[r * 200 + c * 4] = bb;
    }
  } else {
    const bf16x8* X8 = (const bf16x8*)Xv + row0 * 24;
    #pragma unroll
    for (int p = 0; p < 6; ++p) {
      int i = tid + p * 256;                     // 64*24 bf16x8
      int r = i / 24, c = i % 24;
      *(bf16x8*)&Xs[r * 200 + c * 8] = X8[i];
    }
  }
  __syncthreads();

  #pragma unroll
  for (int rg = 0; rg < 4; ++rg) {
    bf16x8 a[6];
    const __bf16* xr = &Xs[(rg * 16 + lr) * 200 + lg * 8];
    #pragma unroll
    for (int kk = 0; kk < 6; ++kk) a[kk] = *(const bf16x8*)&xr[kk * 32];
    #pragma unroll
    for (int t = 0; t < 3; ++t) {
      f32x4 acc = {0.f, 0.f, 0.f, 0.f};
      #pragma unroll
      for (int kk = 0; kk < 6; ++kk) acc = mfma_bf16(a[kk], wf[t][kk], acc);
      const int col = (wv + 4 * t) * 16 + lr;
      const size_t grow = row0 + rg * 16 + lg * 4;
      #pragma unroll
      for (int j = 0; j < 4; ++j) {
        float ov = acc[j] * scale + bcol[t];
        if (OUT_F32) ((float*)Ov)[(grow + j) * 192 + col] = ov;
        else         ((__bf16*)Ov)[(grow + j) * 192 + col] = (__bf16)ov;
      }
    }
  }
}

// ---- attention v2: one block per (b,h); S^T layout, lane-local softmax ----
__global__ __launch_bounds__(256, 3)
void attn2(const __bf16* __restrict__ Q, const __bf16* __restrict__ K,
           const __bf16* __restrict__ V, __bf16* __restrict__ O,
           const float* __restrict__ maskp, const float* __restrict__ btab)
{
  __shared__ float bm2[49 * 52];                  // [q49][k49 wrap-extended 52]
  __shared__ __align__(16) __bf16 Ks[160 * 40];   // [key][d pad40] rows 147+ garbage (masked)
  __shared__ __align__(16) __bf16 Vt[32 * 168];   // [d][key pad168], keys 147-159 zeroed
  __shared__ __align__(16) __bf16 Pl[4 * 16 * 160]; // per-wave [q16][key160], XOR-swizzled

  const int b = blockIdx.x, h = blockIdx.y;
  const int win = b & 63;
  const int tid = threadIdx.x;
  const size_t bOff = (size_t)b * 147;

  // mask + rel-pos bias, k-extended (cols 49..51 duplicate 0..2 for wrap-free +j reads)
  for (int i = tid; i < 49 * 52; i += 256) {
    int q = i / 52, ke = i % 52;
    int k = ke >= 49 ? ke - 49 : ke;
    int qi = q / 7, qj = q - qi * 7, ki = k / 7, kj = k - ki * 7;
    int rel = (qi - ki + 6) * 13 + (qj - kj + 6);
    bm2[i] = maskp[win * 2401 + q * 49 + k] + btab[rel * 6 + h];
  }
  // K staged once (b128 per thread)
  for (int i = tid; i < 147 * 4; i += 256) {
    int row = i >> 2, c = i & 3;
    *(bf16x8*)&Ks[row * 40 + c * 8] =
        *(const bf16x8*)&K[(bOff + row) * 192 + h * 32 + c * 8];
  }
  // V transposed (d-major)
  for (int i = tid; i < 147 * 32; i += 256) {
    int key = i >> 5, d = i & 31;
    Vt[d * 168 + key] = V[(bOff + key) * 192 + h * 32 + d];
  }
  for (int i = tid; i < 32 * 13; i += 256) {      // zero key tail 147..159
    int d = i / 13, key = 147 + (i - (i / 13) * 13);
    Vt[d * 168 + key] = (__bf16)0.f;
  }
  __syncthreads();

  const int wv = tid >> 6, lane = tid & 63;
  const int lr = lane & 15, lg = lane >> 4;
  const uint32_t plbase = (uint32_t)(wv * 16 + lr) * 320;  // 64B-aligned row base
  const uint32_t sw = (uint32_t)(lr & 3) << 4;             // XOR swizzle (bits 4-5)

  for (int mt = wv; mt < 10; mt += 4) {
    int qrow = mt * 16 + lr; if (qrow > 146) qrow = 146;   // clamp (dup rows discarded)
    const bf16x8 qf = *(const bf16x8*)&Q[(bOff + qrow) * 192 + h * 32 + lg * 8];

    // S^T = K @ Q^T : lane holds S[q = mt*16+lr][key = kt*16 + lg*4 + j]
    f32x4 st[10];
    #pragma unroll
    for (int kt = 0; kt < 10; ++kt) {
      bf16x8 kf = *(const bf16x8*)&Ks[(kt * 16 + lr) * 40 + lg * 8];
      f32x4 z = {0.f, 0.f, 0.f, 0.f};
      st[kt] = mfma_bf16(kf, qf, z);
    }

    // + mask + bias (4 consecutive f32 per (kt); wrap-safe via 52-col extension)
    const int q49 = (mt * 16 + lr) % 49;
    const float* bmrow = &bm2[q49 * 52];
    int kb = lg * 4;                               // (kt*16 + lg*4) % 49, incremental
    #pragma unroll
    for (int kt = 0; kt < 10; ++kt) {
      #pragma unroll
      for (int j = 0; j < 4; ++j) st[kt][j] += bmrow[kb + j];
      kb += 16; if (kb >= 49) kb -= 49;
    }
    #pragma unroll
    for (int j = 0; j < 4; ++j)                    // kt=9: keys 144+4lg+j >= 147 invalid
      if (4 * lg + j >= 3) st[9][j] = -1e30f;

    // softmax over keys: 40 lane-local values + cross-lg reduce (2 shuffles)
    float m = st[0][0];
    #pragma unroll
    for (int kt = 0; kt < 10; ++kt)
      #pragma unroll
      for (int j = 0; j < 4; ++j) m = fmaxf(m, st[kt][j]);
    m = fmaxf(m, __shfl_xor(m, 16));
    m = fmaxf(m, __shfl_xor(m, 32));
    const float l2e = 1.44269504088896f;
    const float mm = m * l2e;
    float sum = 0.f;
    #pragma unroll
    for (int kt = 0; kt < 10; ++kt)
      #pragma unroll
      for (int j = 0; j < 4; ++j) {
        float p = exp2f(st[kt][j] * l2e - mm);
        st[kt][j] = p;
        sum += p;
      }
    sum += __shfl_xor(sum, 16);
    sum += __shfl_xor(sum, 32);
    const float rinv = 1.f / sum;

    // P -> Pl as packed bf16 pairs (b32), XOR-swizzled
    #pragma unroll
    for (int kt = 0; kt < 10; ++kt) {
      const uint32_t byte0 = plbase + (uint32_t)(kt * 32 + lg * 8);
      *(uint32_t*)((char*)Pl + ((byte0)     ^ sw)) = pack_bf16(st[kt][0], st[kt][1]);
      *(uint32_t*)((char*)Pl + ((byte0 + 4) ^ sw)) = pack_bf16(st[kt][2], st[kt][3]);
    }

    // O = P @ V  (A from Pl, B from Vt; no barrier: Pl is per-wave)
    f32x4 o0 = {0.f,0.f,0.f,0.f}, o1 = {0.f,0.f,0.f,0.f};
    #pragma unroll
    for (int ks = 0; ks < 5; ++ks) {
      bf16x8 pa = *(const bf16x8*)((const char*)Pl + ((plbase + ks * 64 + lg * 16) ^ sw));
      bf16x8 v0 = *(const bf16x8*)&Vt[lr * 168 + ks * 32 + lg * 8];
      bf16x8 v1 = *(const bf16x8*)&Vt[(16 + lr) * 168 + ks * 32 + lg * 8];
      o0 = mfma_bf16(pa, v0, o0);
      o1 = mfma_bf16(pa, v1, o1);
    }
    #pragma unroll
    for (int j = 0; j < 4; ++j) {
      const int qa = mt * 16 + lg * 4 + j;
      const float rj = __shfl(rinv, lg * 4 + j);   // row sums live at lanes 0-15
      if (qa < 147) {
        const size_t base = (bOff + qa) * 192 + h * 32;
        O[base + lr]      = (__bf16)(o0[j] * rj);
        O[base + 16 + lr] = (__bf16)(o1[j] * rj);
      }
    }
  }
}

extern "C" void kernel_launch(void* const* d_in, const int* in_sizes, int n_in,
                              void* d_out, int out_size, void* d_ws, size_t ws_size,
                              hipStream_t stream) {
  (void)in_sizes; (void)n_in; (void)out_size;
  const float* x_q  = (const float*)d_in[0];
  const float* x_k  = (const float*)d_in[1];
  const float* x_v  = (const float*)d_in[2];
  const float* maskp= (const float*)d_in[3];
  const float* q_w  = (const float*)d_in[4];
  const float* q_b  = (const float*)d_in[5];
  const float* k_w  = (const float*)d_in[6];
  const float* k_b  = (const float*)d_in[7];
  const float* v_w  = (const float*)d_in[8];
  const float* v_b  = (const float*)d_in[9];
  const float* p_w  = (const float*)d_in[10];
  const float* p_b  = (const float*)d_in[11];
  const float* btab = (const float*)d_in[12];

  char* ws = (char*)d_ws;
  const size_t wsz = 36864 * sizeof(__bf16);     // one 192x192 bf16 weight
  __bf16* wq = (__bf16*)ws;
  __bf16* wk = (__bf16*)(ws + wsz);
  __bf16* wvp = (__bf16*)(ws + 2 * wsz);
  __bf16* wp = (__bf16*)(ws + 3 * wsz);
  char* bufs = ws + 4 * wsz;
  const size_t sz = (size_t)ROWS * 192 * sizeof(__bf16);   // 57.8 MB
  __bf16* qb = (__bf16*)bufs;
  __bf16* kb = (__bf16*)(bufs + sz);
  __bf16* vb = (__bf16*)(bufs + 2 * sz);
  __bf16* ob = (ws_size >= 4 * wsz + 4 * sz) ? (__bf16*)(bufs + 3 * sz) : qb;

  cvt4<<<dim3(36, 4), 256, 0, stream>>>(q_w, k_w, v_w, p_w, wq, wk, wvp, wp);

  gemmv2<true, false><<<ROWS / 64, 256, 0, stream>>>(x_q, wq, q_b, qb, QSCALE);
  gemmv2<true, false><<<ROWS / 64, 256, 0, stream>>>(x_k, wk, k_b, kb, 1.f);
  gemmv2<true, false><<<ROWS / 64, 256, 0, stream>>>(x_v, wvp, v_b, vb, 1.f);

  attn2<<<dim3(1024, 6), 256, 0, stream>>>(qb, kb, vb, ob, maskp, btab);

  gemmv2<false, true><<<ROWS / 64, 256, 0, stream>>>(ob, wp, p_b, d_out, 1.f);
}

// Round 3
// 357.114 us; speedup vs baseline: 1.7389x; 1.2217x over previous
//
#include <hip/hip_runtime.h>
#include <stdint.h>

#define ROWS 150528              // 1024 * 147
#define QSCALE 0.17677669529663687f

typedef __attribute__((ext_vector_type(8))) __bf16 bf16x8;
typedef __attribute__((ext_vector_type(4))) __bf16 bf16x4;
typedef __attribute__((ext_vector_type(4))) float f32x4;
typedef __attribute__((ext_vector_type(4))) float f4;
typedef __attribute__((ext_vector_type(2))) uint32_t u32x2;

static __device__ __forceinline__ f32x4 mfma_bf16(bf16x8 a, bf16x8 b, f32x4 c) {
  return __builtin_amdgcn_mfma_f32_16x16x32_bf16(a, b, c, 0, 0, 0);
}

static __device__ __forceinline__ uint32_t pack_bf16(float a, float b) {
  uint16_t ux = __builtin_bit_cast(uint16_t, (__bf16)a);
  uint16_t uy = __builtin_bit_cast(uint16_t, (__bf16)b);
  return (uint32_t)ux | ((uint32_t)uy << 16);
}

// ---- convert 4 f32 weights -> bf16 in one launch: grid (36, 4) ----
__global__ void cvt4(const float* s0, const float* s1, const float* s2, const float* s3,
                     __bf16* d0, __bf16* d1, __bf16* d2, __bf16* d3) {
  const int y = blockIdx.y;
  const float* s = y == 0 ? s0 : y == 1 ? s1 : y == 2 ? s2 : s3;
  __bf16* d = y == 0 ? d0 : y == 1 ? d1 : y == 2 ? d2 : d3;
  int i = blockIdx.x * 256 + threadIdx.x;        // 9216 float4 groups
  f4 v = ((const f4*)s)[i];
  bf16x4 b;
  b[0] = (__bf16)v[0]; b[1] = (__bf16)v[1]; b[2] = (__bf16)v[2]; b[3] = (__bf16)v[3];
  ((bf16x4*)d)[i] = b;
}

// ---- precompute combined (mask + rel-pos bias): grid (64 windows, 6 heads) ----
// layout: bmall[(win*6+h)*2600 + q*53 + ke], ke in [0,52) with cols 49..51 = wrap dup
__global__ void bmpre(const float* __restrict__ maskp, const float* __restrict__ btab,
                      float* __restrict__ bmall) {
  const int win = blockIdx.x, h = blockIdx.y;
  float* dst = bmall + ((size_t)(win * 6 + h)) * 2600;
  for (int i = threadIdx.x; i < 2597; i += 256) {
    int q = i / 53, ke = i - q * 53;
    int k = ke >= 49 ? ke - 49 : ke;
    int qi = q / 7, qj = q - qi * 7, ki = k / 7, kj = k - ki * 7;
    int rel = (qi - ki + 6) * 13 + (qj - kj + 6);
    dst[i] = maskp[win * 2401 + q * 49 + k] + btab[rel * 6 + h];
  }
}

// ---- GEMM v2 (unchanged): out[M x 192] = X[M x 192] @ W^T + bias ----
template<bool IN_F32, bool OUT_F32>
__global__ __launch_bounds__(256, 3)
void gemmv2(const void* __restrict__ Xv, const __bf16* __restrict__ Wb,
            const float* __restrict__ bias, void* __restrict__ Ov, float scale)
{
  __shared__ __align__(16) __bf16 Xs[64 * 200];   // pad 192->200
  const int tid = threadIdx.x;
  const int wv = tid >> 6, lane = tid & 63, lr = lane & 15, lg = lane >> 4;
  const size_t row0 = (size_t)blockIdx.x * 64;

  bf16x8 wf[3][6];
  float bcol[3];
  #pragma unroll
  for (int t = 0; t < 3; ++t) {
    const int nt = wv + 4 * t;
    const __bf16* wr = &Wb[(nt * 16 + lr) * 192 + lg * 8];
    #pragma unroll
    for (int kk = 0; kk < 6; ++kk) wf[t][kk] = *(const bf16x8*)&wr[kk * 32];
    bcol[t] = bias[nt * 16 + lr] * scale;
  }

  if (IN_F32) {
    const f4* X4 = (const f4*)Xv + row0 * 48;
    #pragma unroll
    for (int p = 0; p < 12; ++p) {
      int i = tid + p * 256;
      int r = i / 48, c = i % 48;
      f4 v = X4[i];
      bf16x4 bb;
      bb[0] = (__bf16)v[0]; bb[1] = (__bf16)v[1]; bb[2] = (__bf16)v[2]; bb[3] = (__bf16)v[3];
      *(bf16x4*)&Xs[r * 200 + c * 4] = bb;
    }
  } else {
    const bf16x8* X8 = (const bf16x8*)Xv + row0 * 24;
    #pragma unroll
    for (int p = 0; p < 6; ++p) {
      int i = tid + p * 256;
      int r = i / 24, c = i % 24;
      *(bf16x8*)&Xs[r * 200 + c * 8] = X8[i];
    }
  }
  __syncthreads();

  #pragma unroll
  for (int rg = 0; rg < 4; ++rg) {
    bf16x8 a[6];
    const __bf16* xr = &Xs[(rg * 16 + lr) * 200 + lg * 8];
    #pragma unroll
    for (int kk = 0; kk < 6; ++kk) a[kk] = *(const bf16x8*)&xr[kk * 32];
    #pragma unroll
    for (int t = 0; t < 3; ++t) {
      f32x4 acc = {0.f, 0.f, 0.f, 0.f};
      #pragma unroll
      for (int kk = 0; kk < 6; ++kk) acc = mfma_bf16(a[kk], wf[t][kk], acc);
      const int col = (wv + 4 * t) * 16 + lr;
      const size_t grow = row0 + rg * 16 + lg * 4;
      #pragma unroll
      for (int j = 0; j < 4; ++j) {
        float ov = acc[j] * scale + bcol[t];
        if (OUT_F32) ((float*)Ov)[(grow + j) * 192 + col] = ov;
        else         ((__bf16*)Ov)[(grow + j) * 192 + col] = (__bf16)ov;
      }
    }
  }
}

// ---- attention v3 ----
// LDS layout (manual, 53,376 B -> 3 blocks/CU):
//   Pl  [0      .. 20480)  : per-wave P tile, 16 rows x 320B, XOR (lr&3)<<4
//   Ks  [20480  .. 32240)  : K [147][40], 80B rows (2-way free)
//   Vt  [32240  .. 42992)  : V^T [32][168], 336B rows (21x16B odd -> reads free)
//   bm2 [42992  .. 53376)  : 2596 f32, stride 53 (odd words -> gathers 2-way free)
__global__ __launch_bounds__(256, 3)
void attn3(const __bf16* Q, const __bf16* __restrict__ K,
           const __bf16* __restrict__ V, __bf16* __restrict__ O,
           const float* __restrict__ bmall)
{
  __shared__ __align__(16) char smem[53376];
  char* PlB = smem;
  __bf16* Ks = (__bf16*)(smem + 20480);
  __bf16* Vt = (__bf16*)(smem + 32240);
  float* bm2 = (float*)(smem + 42992);

  const int b = blockIdx.x, h = blockIdx.y;
  const int win = b & 63;
  const int tid = threadIdx.x;
  const size_t bOff = (size_t)b * 147;

  const int wv = tid >> 6, lane = tid & 63;
  const int lr = lane & 15, lg = lane >> 4;

  // ---- prefetch Q fragments for this wave's tiles (before any LDS/barrier) ----
  const int nmt = (wv < 2) ? 3 : 2;
  bf16x8 qf[3];
  #pragma unroll
  for (int t = 0; t < 3; ++t) {
    int mt = wv + 4 * t; if (mt > 9) mt = 9;
    int qrow = mt * 16 + lr; if (qrow > 146) qrow = 146;
    qf[t] = *(const bf16x8*)&Q[(bOff + qrow) * 192 + h * 32 + lg * 8];
  }

  // ---- staging ----
  // bm: 649 float4 coalesced copies from precomputed table
  {
    const f4* bsrc = (const f4*)(bmall + ((size_t)(win * 6 + h)) * 2600);
    f4* bdst = (f4*)bm2;
    for (int i = tid; i < 649; i += 256) bdst[i] = bsrc[i];
  }
  // K: b128 copies, [147][40]
  for (int i = tid; i < 147 * 4; i += 256) {
    int row = i >> 2, c = i & 3;
    *(bf16x8*)&Ks[row * 40 + c * 8] =
        *(const bf16x8*)&K[(bOff + row) * 192 + h * 32 + c * 8];
  }
  // V: b128 global load + LDS transpose scatter, [32][168]
  for (int t = tid; t < 147 * 4; t += 256) {
    int key = t >> 2, dblk = t & 3;
    bf16x8 v = *(const bf16x8*)&V[(bOff + key) * 192 + h * 32 + dblk * 8];
    #pragma unroll
    for (int e = 0; e < 8; ++e) Vt[(dblk * 8 + e) * 168 + key] = v[e];
  }
  for (int i = tid; i < 32 * 13; i += 256) {      // zero key tail 147..159
    int d = i / 13, key = 147 + (i - (i / 13) * 13);
    Vt[d * 168 + key] = (__bf16)0.f;
  }
  __syncthreads();

  const uint32_t plbase = (uint32_t)(wv * 16 + lr) * 320;
  const uint32_t sw = (uint32_t)(lr & 3) << 4;

  for (int t = 0; t < nmt; ++t) {
    const int mt = wv + 4 * t;

    // S^T = K @ Q^T : lane holds S[q=mt*16+lr][key=kt*16+lg*4+j]
    f32x4 st[10];
    #pragma unroll
    for (int kt = 0; kt < 10; ++kt) {
      bf16x8 kf = *(const bf16x8*)&Ks[(kt * 16 + lr) * 40 + lg * 8];
      f32x4 z = {0.f, 0.f, 0.f, 0.f};
      st[kt] = mfma_bf16(kf, qf[t], z);
    }

    // + (mask+bias), stride-53 rows, wrap-extended cols
    const int q49 = (mt * 16 + lr) % 49;
    const float* bmrow = &bm2[q49 * 53];
    int kb = lg * 4;
    #pragma unroll
    for (int kt = 0; kt < 10; ++kt) {
      #pragma unroll
      for (int j = 0; j < 4; ++j) st[kt][j] += bmrow[kb + j];
      kb += 16; if (kb >= 49) kb -= 49;
    }
    #pragma unroll
    for (int j = 0; j < 4; ++j)                    // keys 144+4lg+j >= 147 invalid
      if (4 * lg + j >= 3) st[9][j] = -1e30f;

    // softmax over keys: 40 lane-local + 2-shuffle cross-lg reduce
    float m = st[0][0];
    #pragma unroll
    for (int kt = 0; kt < 10; ++kt)
      #pragma unroll
      for (int j = 0; j < 4; ++j) m = fmaxf(m, st[kt][j]);
    m = fmaxf(m, __shfl_xor(m, 16));
    m = fmaxf(m, __shfl_xor(m, 32));
    const float l2e = 1.44269504088896f;
    const float mm = m * l2e;
    float sum = 0.f;
    #pragma unroll
    for (int kt = 0; kt < 10; ++kt)
      #pragma unroll
      for (int j = 0; j < 4; ++j) {
        float p = exp2f(st[kt][j] * l2e - mm);
        st[kt][j] = p;
        sum += p;
      }
    sum += __shfl_xor(sum, 16);
    sum += __shfl_xor(sum, 32);
    const float rinv = 1.f / sum;

    // P -> Pl as b64 packed bf16 quads
    #pragma unroll
    for (int kt = 0; kt < 10; ++kt) {
      u32x2 pw;
      pw[0] = pack_bf16(st[kt][0], st[kt][1]);
      pw[1] = pack_bf16(st[kt][2], st[kt][3]);
      *(u32x2*)(PlB + ((plbase + (uint32_t)(kt * 32 + lg * 8)) ^ sw)) = pw;
    }

    // O = P @ V (per-wave Pl, no barrier)
    f32x4 o0 = {0.f,0.f,0.f,0.f}, o1 = {0.f,0.f,0.f,0.f};
    #pragma unroll
    for (int ks = 0; ks < 5; ++ks) {
      bf16x8 pa = *(const bf16x8*)(PlB + ((plbase + (uint32_t)(ks * 64 + lg * 16)) ^ sw));
      bf16x8 v0 = *(const bf16x8*)&Vt[lr * 168 + ks * 32 + lg * 8];
      bf16x8 v1 = *(const bf16x8*)&Vt[(16 + lr) * 168 + ks * 32 + lg * 8];
      o0 = mfma_bf16(pa, v0, o0);
      o1 = mfma_bf16(pa, v1, o1);
    }
    #pragma unroll
    for (int j = 0; j < 4; ++j) {
      const int qa = mt * 16 + lg * 4 + j;
      const float rj = __shfl(rinv, lg * 4 + j);
      if (qa < 147) {
        const size_t base = (bOff + qa) * 192 + h * 32;
        O[base + lr]      = (__bf16)(o0[j] * rj);
        O[base + 16 + lr] = (__bf16)(o1[j] * rj);
      }
    }
  }
}

extern "C" void kernel_launch(void* const* d_in, const int* in_sizes, int n_in,
                              void* d_out, int out_size, void* d_ws, size_t ws_size,
                              hipStream_t stream) {
  (void)in_sizes; (void)n_in; (void)out_size;
  const float* x_q  = (const float*)d_in[0];
  const float* x_k  = (const float*)d_in[1];
  const float* x_v  = (const float*)d_in[2];
  const float* maskp= (const float*)d_in[3];
  const float* q_w  = (const float*)d_in[4];
  const float* q_b  = (const float*)d_in[5];
  const float* k_w  = (const float*)d_in[6];
  const float* k_b  = (const float*)d_in[7];
  const float* v_w  = (const float*)d_in[8];
  const float* v_b  = (const float*)d_in[9];
  const float* p_w  = (const float*)d_in[10];
  const float* p_b  = (const float*)d_in[11];
  const float* btab = (const float*)d_in[12];

  char* ws = (char*)d_ws;
  // [bmall 4MB][4 weights][qb][kb][vb][ob?]
  float* bmall = (float*)ws;
  const size_t bmsz = (size_t)64 * 6 * 2600 * sizeof(float);   // 3,993,600
  char* wsp = ws + bmsz;
  const size_t wsz = 36864 * sizeof(__bf16);
  __bf16* wq  = (__bf16*)wsp;
  __bf16* wk  = (__bf16*)(wsp + wsz);
  __bf16* wvp = (__bf16*)(wsp + 2 * wsz);
  __bf16* wp  = (__bf16*)(wsp + 3 * wsz);
  char* bufs = wsp + 4 * wsz;
  const size_t sz = (size_t)ROWS * 192 * sizeof(__bf16);       // 57.8 MB
  __bf16* qb = (__bf16*)bufs;
  __bf16* kb = (__bf16*)(bufs + sz);
  __bf16* vb = (__bf16*)(bufs + 2 * sz);
  const size_t need4 = bmsz + 4 * wsz + 4 * sz;
  __bf16* ob = (ws_size >= need4) ? (__bf16*)(bufs + 3 * sz) : qb;

  cvt4<<<dim3(36, 4), 256, 0, stream>>>(q_w, k_w, v_w, p_w, wq, wk, wvp, wp);
  bmpre<<<dim3(64, 6), 256, 0, stream>>>(maskp, btab, bmall);

  gemmv2<true, false><<<ROWS / 64, 256, 0, stream>>>(x_q, wq, q_b, qb, QSCALE);
  gemmv2<true, false><<<ROWS / 64, 256, 0, stream>>>(x_k, wk, k_b, kb, 1.f);
  gemmv2<true, false><<<ROWS / 64, 256, 0, stream>>>(x_v, wvp, v_b, vb, 1.f);

  attn3<<<dim3(1024, 6), 256, 0, stream>>>(qb, kb, vb, ob, bmall);

  gemmv2<false, true><<<ROWS / 64, 256, 0, stream>>>(ob, wp, p_b, d_out, 1.f);
}